// Round 7
// baseline (358.118 us; speedup 1.0000x reference)
//
#include <hip/hip_runtime.h>
#include <math.h>

typedef _Float16 f16;
typedef __attribute__((ext_vector_type(8))) _Float16 f16x8;
typedef __attribute__((ext_vector_type(4))) _Float16 f16x4;
typedef __attribute__((ext_vector_type(4))) float f32x4;

constexpr int BATCH = 32;
constexpr int QL = 1024;
constexpr int KL = 1024;
constexpr int D = 128;
constexpr int BQ = 128;   // query rows per block: 4 waves x 32 rows
constexpr int BK = 64;    // key rows per tile
constexpr int NCHT = 4;   // tiles per split-K chunk (256 keys)
constexpr int DKP = 136;  // sK row pitch in halves (272 B)
constexpr int BKP = 72;   // sVT/sP row pitch in halves (144 B)
constexpr int NQT = QL / BQ;          // 8 q-tiles
constexpr size_t SLOT = 512 + 512 + (size_t)D * BQ * 4;  // m,l,O fp32 = 66560 B
constexpr size_t WS_PART_OFF = 4096;

// scale * log2(e): softmax computed in exp2 domain
#define CSC 0.12752863187087177f

static __device__ __forceinline__ f16x4 pk4(float x, float y, float z, float w) {
  auto a = __builtin_amdgcn_cvt_pkrtz(x, y);   // __fp16 ext_vector(2)
  auto b = __builtin_amdgcn_cvt_pkrtz(z, w);
  f16x4 h;
  h[0] = (f16)a[0]; h[1] = (f16)a[1]; h[2] = (f16)b[0]; h[3] = (f16)b[1];
  return h;
}

__global__ void zero_cnt(int* cnt) { cnt[threadIdx.x] = 0; }

__global__ __launch_bounds__(256, 2)
void attn_fwd(const float* __restrict__ Qp, const float* __restrict__ Kp,
              const float* __restrict__ Vp, const int* __restrict__ VLp,
              float* __restrict__ Op, char* __restrict__ ws, int nclog) {
  // single-buffered tiles (54 KB LDS -> 2 blocks/CU = 2 waves/SIMD)
  __shared__ f16 sK[BK][DKP];    // ROW-PERMUTED: pos p holds key (p&15)*4+(p>>4)
  __shared__ f16 sVT[D][BKP];    // V tile transposed [d][kk]
  __shared__ f16 sP[4][32][BKP]; // per-wave P tile [row][kk]
  __shared__ int sLast;

  const int tid  = threadIdx.x;
  const int wave = tid >> 6, lane = tid & 63;
  const int l16  = lane & 15, quad = lane >> 4;

  // XCD-affinity: id%8 == b%8 -> all chunks of (b,qt) share one XCD L2
  const int id   = blockIdx.x;
  const int b    = (((id >> 3) & 3) << 3) | (id & 7);
  const int rest = id >> 5;
  const int nch  = 1 << nclog;
  const int ch   = rest & (nch - 1);
  const int qt   = rest >> nclog;
  const int vl   = VLp[b];

  const int ntiles  = (vl + BK - 1) / BK;            // 1..16
  const int nchunks = (nclog == 0) ? 1 : (ntiles + NCHT - 1) / NCHT;
  if (ch >= nchunks) return;                         // cheap early exit
  const int t0   = ch * NCHT;
  const int tend = (nclog == 0) ? ntiles : min(t0 + NCHT, ntiles);

  const float* Kb = Kp + (size_t)b * KL * D;
  const float* Vb = Vp + (size_t)b * KL * D;

  float4 kreg[8], vreg[8];

  // ---- prologue: load tile t0 into regs
  {
    const float4* Kt = (const float4*)(Kb + (size_t)t0 * BK * D);
    #pragma unroll
    for (int i = 0; i < 8; ++i) kreg[i] = Kt[tid + i * 256];
    const float* Vt = Vb + (size_t)t0 * BK * D;
    #pragma unroll
    for (int i = 0; i < 2; ++i) {
      int f = tid + i * 256;
      const float* base = Vt + (size_t)((f & 15) * 4) * D + (f >> 4) * 4;
      vreg[i * 4 + 0] = *(const float4*)(base);
      vreg[i * 4 + 1] = *(const float4*)(base + D);
      vreg[i * 4 + 2] = *(const float4*)(base + 2 * D);
      vreg[i * 4 + 3] = *(const float4*)(base + 3 * D);
    }
  }

  // ---- Q fragments: 2 row-groups (mt) x 4 k-chunks, registers for all tiles
  f16x8 qfrag[2][4];
  #pragma unroll
  for (int mt = 0; mt < 2; ++mt) {
    const float* Qb =
        Qp + ((size_t)(b * QL + qt * BQ + wave * 32 + mt * 16 + l16)) * D;
    #pragma unroll
    for (int kc = 0; kc < 4; ++kc) {
      const float* p = Qb + kc * 32 + quad * 8;
      float4 u = *(const float4*)p;
      float4 v = *(const float4*)(p + 4);
      f16x4 h0 = pk4(u.x, u.y, u.z, u.w);
      f16x4 h1 = pk4(v.x, v.y, v.z, v.w);
      f16x8 f;
      f[0] = h0[0]; f[1] = h0[1]; f[2] = h0[2]; f[3] = h0[3];
      f[4] = h1[0]; f[5] = h1[1]; f[6] = h1[2]; f[7] = h1[3];
      qfrag[mt][kc] = f;
    }
  }

  float m2[2][4], lsum[2][4];
  f32x4 o[2][8];
  #pragma unroll
  for (int mt = 0; mt < 2; ++mt)
    #pragma unroll
    for (int r = 0; r < 4; ++r) { m2[mt][r] = -INFINITY; lsum[mt][r] = 0.f; }
  #pragma unroll
  for (int mt = 0; mt < 2; ++mt)
    #pragma unroll
    for (int dt = 0; dt < 8; ++dt) o[mt][dt] = (f32x4){0.f, 0.f, 0.f, 0.f};

  // ---- drain tile t0 into LDS
  #pragma unroll
  for (int i = 0; i < 8; ++i) {
    int row = (tid + i * 256) >> 5;
    int rp = (row & 3) * 16 + (row >> 2);
    float4 u = kreg[i];
    *(f16x4*)&sK[rp][(tid & 31) * 4] = pk4(u.x, u.y, u.z, u.w);
  }
  #pragma unroll
  for (int i = 0; i < 2; ++i) {
    int f = tid + i * 256;
    int k0 = (f & 15) * 4, d0 = (f >> 4) * 4;
    float4 r0 = vreg[i*4+0], r1 = vreg[i*4+1], r2 = vreg[i*4+2], r3 = vreg[i*4+3];
    *(f16x4*)&sVT[d0 + 0][k0] = pk4(r0.x, r1.x, r2.x, r3.x);
    *(f16x4*)&sVT[d0 + 1][k0] = pk4(r0.y, r1.y, r2.y, r3.y);
    *(f16x4*)&sVT[d0 + 2][k0] = pk4(r0.z, r1.z, r2.z, r3.z);
    *(f16x4*)&sVT[d0 + 3][k0] = pk4(r0.w, r1.w, r2.w, r3.w);
  }
  __syncthreads();

  for (int t = t0; t < tend; ++t) {
    const bool more = (t + 1 < tend);

    // ---- issue global loads for tile t+1 (land during compute)
    if (more) {
      const float4* Kt = (const float4*)(Kb + (size_t)(t + 1) * BK * D);
      #pragma unroll
      for (int i = 0; i < 8; ++i) kreg[i] = Kt[tid + i * 256];
      const float* Vt = Vb + (size_t)(t + 1) * BK * D;
      #pragma unroll
      for (int i = 0; i < 2; ++i) {
        int f = tid + i * 256;
        const float* base = Vt + (size_t)((f & 15) * 4) * D + (f >> 4) * 4;
        vreg[i * 4 + 0] = *(const float4*)(base);
        vreg[i * 4 + 1] = *(const float4*)(base + D);
        vreg[i * 4 + 2] = *(const float4*)(base + 2 * D);
        vreg[i * 4 + 3] = *(const float4*)(base + 3 * D);
      }
    }

    // ---- S = Q K^T : 2 mt x 4 ct x 4 kc MFMA; kf reads shared across mt
    f32x4 s[2][4];
    #pragma unroll
    for (int ct = 0; ct < 4; ++ct) {
      f32x4 c0 = (f32x4){0.f, 0.f, 0.f, 0.f};
      f32x4 c1 = (f32x4){0.f, 0.f, 0.f, 0.f};
      #pragma unroll
      for (int kc = 0; kc < 4; ++kc) {
        f16x8 kf = *(const f16x8*)&sK[ct * 16 + l16][kc * 32 + quad * 8];
        c0 = __builtin_amdgcn_mfma_f32_16x16x32_f16(qfrag[0][kc], kf, c0, 0, 0, 0);
        c1 = __builtin_amdgcn_mfma_f32_16x16x32_f16(qfrag[1][kc], kf, c1, 0, 0, 0);
      }
      s[0][ct] = c0;
      s[1][ct] = c1;
    }

    // ---- scale into log2 domain + key-padding mask (kk = t*64 + l16*4 + ct)
    #pragma unroll
    for (int ct = 0; ct < 4; ++ct) {
      bool ok = (t * BK + l16 * 4 + ct) < vl;
      #pragma unroll
      for (int mt = 0; mt < 2; ++mt)
        #pragma unroll
        for (int r = 0; r < 4; ++r)
          s[mt][ct][r] = ok ? s[mt][ct][r] * CSC : -1.0e9f;
    }

    // ---- online softmax per mt (16-lane group owns rows quad*4+r)
    #pragma unroll
    for (int mt = 0; mt < 2; ++mt) {
      float mnew[4], alpha[4], ls[4];
      #pragma unroll
      for (int r = 0; r < 4; ++r) {
        float v = fmaxf(fmaxf(s[mt][0][r], s[mt][1][r]),
                        fmaxf(s[mt][2][r], s[mt][3][r]));
        v = fmaxf(v, __shfl_xor(v, 1));
        v = fmaxf(v, __shfl_xor(v, 2));
        v = fmaxf(v, __shfl_xor(v, 4));
        v = fmaxf(v, __shfl_xor(v, 8));
        mnew[r]  = fmaxf(m2[mt][r], v);
        alpha[r] = __builtin_amdgcn_exp2f(m2[mt][r] - mnew[r]);
        m2[mt][r] = mnew[r];
        ls[r] = 0.f;
      }
      #pragma unroll
      for (int ct = 0; ct < 4; ++ct)
        #pragma unroll
        for (int r = 0; r < 4; ++r) {
          float p = __builtin_amdgcn_exp2f(s[mt][ct][r] - mnew[r]);
          s[mt][ct][r] = p;
          ls[r] += p;
        }
      #pragma unroll
      for (int r = 0; r < 4; ++r) {
        float v = ls[r];
        v += __shfl_xor(v, 1);
        v += __shfl_xor(v, 2);
        v += __shfl_xor(v, 4);
        v += __shfl_xor(v, 8);
        lsum[mt][r] = lsum[mt][r] * alpha[r] + v;
        // P -> LDS: 4 ct-values are kk-contiguous (l16*4+ct) -> ds_write_b64
        *(f16x4*)&sP[wave][mt * 16 + quad * 4 + r][l16 * 4] =
            pk4(s[mt][0][r], s[mt][1][r], s[mt][2][r], s[mt][3][r]);
        #pragma unroll
        for (int dt = 0; dt < 8; ++dt) o[mt][dt][r] *= alpha[r];
      }
    }

    // sP is wave-private: in-wave DS ordering + waitcnt suffices (no barrier)
    asm volatile("s_waitcnt lgkmcnt(0)" ::: "memory");

    // ---- O += P V : vf reads shared across mt
    #pragma unroll
    for (int ks = 0; ks < 2; ++ks) {
      f16x8 pf0 = *(const f16x8*)&sP[wave][l16][ks * 32 + quad * 8];
      f16x8 pf1 = *(const f16x8*)&sP[wave][16 + l16][ks * 32 + quad * 8];
      #pragma unroll
      for (int dt = 0; dt < 8; ++dt) {
        f16x8 vf = *(const f16x8*)&sVT[dt * 16 + l16][ks * 32 + quad * 8];
        o[0][dt] = __builtin_amdgcn_mfma_f32_16x16x32_f16(pf0, vf, o[0][dt], 0, 0, 0);
        o[1][dt] = __builtin_amdgcn_mfma_f32_16x16x32_f16(pf1, vf, o[1][dt], 0, 0, 0);
      }
    }

    // ---- 2-barrier drain of prefetched regs into the (single) buffers
    if (more) {
      __syncthreads();   // all waves done reading sK/sVT for tile t
      #pragma unroll
      for (int i = 0; i < 8; ++i) {
        int row = (tid + i * 256) >> 5;
        int rp = (row & 3) * 16 + (row >> 2);
        float4 u = kreg[i];
        *(f16x4*)&sK[rp][(tid & 31) * 4] = pk4(u.x, u.y, u.z, u.w);
      }
      #pragma unroll
      for (int i = 0; i < 2; ++i) {
        int f = tid + i * 256;
        int k0 = (f & 15) * 4, d0 = (f >> 4) * 4;
        float4 r0 = vreg[i*4+0], r1 = vreg[i*4+1], r2 = vreg[i*4+2], r3 = vreg[i*4+3];
        *(f16x4*)&sVT[d0 + 0][k0] = pk4(r0.x, r1.x, r2.x, r3.x);
        *(f16x4*)&sVT[d0 + 1][k0] = pk4(r0.y, r1.y, r2.y, r3.y);
        *(f16x4*)&sVT[d0 + 2][k0] = pk4(r0.z, r1.z, r2.z, r3.z);
        *(f16x4*)&sVT[d0 + 3][k0] = pk4(r0.w, r1.w, r2.w, r3.w);
      }
      __syncthreads();
    }
  }

  // ======== epilogue ========
  if (nchunks == 1) {
    float* Ob = Op + ((size_t)(b * QL + qt * BQ + wave * 32)) * D;
    #pragma unroll
    for (int mt = 0; mt < 2; ++mt)
      #pragma unroll
      for (int r = 0; r < 4; ++r) {
        float inv = 1.0f / lsum[mt][r];
        int row = mt * 16 + quad * 4 + r;
        #pragma unroll
        for (int dt = 0; dt < 8; ++dt)
          Ob[(size_t)row * D + dt * 16 + l16] = o[mt][dt][r] * inv;
      }
    return;
  }

  // ---- split-K: write partial (m, l, O) in log2 domain to workspace
  const int cIdx = b * NQT + qt;
  char* slot0 = ws + WS_PART_OFF + (size_t)(cIdx * NCHT) * SLOT;
  {
    char* slot = slot0 + (size_t)ch * SLOT;
    float* mS = (float*)slot;
    float* lS = (float*)(slot + 512);
    float* OS = (float*)(slot + 1024);
    #pragma unroll
    for (int mt = 0; mt < 2; ++mt)
      #pragma unroll
      for (int r = 0; r < 4; ++r) {
        int rl = wave * 32 + mt * 16 + quad * 4 + r;
        if (l16 == 0) { mS[rl] = m2[mt][r]; lS[rl] = lsum[mt][r]; }
        #pragma unroll
        for (int dt = 0; dt < 8; ++dt)
          OS[(size_t)rl * D + dt * 16 + l16] = o[mt][dt][r];
      }
  }
  __threadfence();      // release: partial visible device-wide (same XCD anyway)
  __syncthreads();      // all threads' stores fenced before the count
  if (tid == 0) {
    int old = atomicAdd((int*)ws + cIdx, 1);
    sLast = (old == nchunks - 1) ? 1 : 0;
  }
  __syncthreads();
  if (!sLast) return;
  __threadfence();      // acquire: see all other chunks' partials

  // ---- merge: this block reduces all nchunks partials and writes O
  float* Ob = Op + ((size_t)(b * QL + qt * BQ)) * D;
  #pragma unroll
  for (int mt = 0; mt < 2; ++mt)
    #pragma unroll
    for (int r = 0; r < 4; ++r) {
      int rl = wave * 32 + mt * 16 + quad * 4 + r;
      float M = -INFINITY;
      for (int i = 0; i < nchunks; ++i)
        M = fmaxf(M, *(const float*)(slot0 + (size_t)i * SLOT + rl * 4));
      float a[4];
      float L = 0.f;
      for (int i = 0; i < nchunks; ++i) {
        const char* sl = slot0 + (size_t)i * SLOT;
        a[i] = __builtin_amdgcn_exp2f(*(const float*)(sl + rl * 4) - M);
        L += *(const float*)(sl + 512 + rl * 4) * a[i];
      }
      float inv = 1.0f / L;
      #pragma unroll
      for (int dt = 0; dt < 8; ++dt) {
        int col = dt * 16 + l16;
        float acc = 0.f;
        for (int i = 0; i < nchunks; ++i)
          acc += ((const float*)(slot0 + (size_t)i * SLOT + 1024))[(size_t)rl * D + col] * a[i];
        Ob[(size_t)rl * D + col] = acc * inv;
      }
    }
}

extern "C" void kernel_launch(void* const* d_in, const int* in_sizes, int n_in,
                              void* d_out, int out_size, void* d_ws, size_t ws_size,
                              hipStream_t stream) {
  const float* Qp = (const float*)d_in[0];
  const float* Kp = (const float*)d_in[1];
  const float* Vp = (const float*)d_in[2];
  const int*   VL = (const int*)d_in[3];
  float* Op = (float*)d_out;

  const size_t need = WS_PART_OFF + (size_t)BATCH * NQT * NCHT * SLOT;  // ~68 MB
  const int nclog = (ws_size >= need) ? 2 : 0;

  if (nclog) zero_cnt<<<1, BATCH * NQT, 0, stream>>>((int*)d_ws);
  const int grid = BATCH * NQT * (1 << nclog);
  attn_fwd<<<dim3(grid), dim3(256), 0, stream>>>(Qp, Kp, Vp, VL, Op,
                                                 (char*)d_ws, nclog);
}

// Round 8
// 120.847 us; speedup vs baseline: 2.9634x; 2.9634x over previous
//
#include <hip/hip_runtime.h>
#include <math.h>

typedef _Float16 f16;
typedef __attribute__((ext_vector_type(8))) _Float16 f16x8;
typedef __attribute__((ext_vector_type(4))) _Float16 f16x4;
typedef __attribute__((ext_vector_type(4))) float f32x4;

constexpr int BATCH = 32;
constexpr int QL = 1024;
constexpr int KL = 1024;
constexpr int D = 128;
constexpr int BQ = 64;    // query rows per block (16 per wave)
constexpr int BK = 64;    // key rows per tile
constexpr int DKP = 136;  // sK row pitch in halves (272 B, 16B-aligned rows)
constexpr int BKP = 72;   // sVT/sP row pitch in halves (144 B)

// scale * log2(e): softmax computed in exp2 domain
#define CSC 0.12752863187087177f

static __device__ __forceinline__ f16x4 pk4(float x, float y, float z, float w) {
  auto a = __builtin_amdgcn_cvt_pkrtz(x, y);
  auto b = __builtin_amdgcn_cvt_pkrtz(z, w);
  f16x4 h;
  h[0] = (f16)a[0]; h[1] = (f16)a[1]; h[2] = (f16)b[0]; h[3] = (f16)b[1];
  return h;
}
static __device__ __forceinline__ f16x8 pk8(float4 u, float4 v) {
  f16x4 a = pk4(u.x, u.y, u.z, u.w);
  f16x4 b = pk4(v.x, v.y, v.z, v.w);
  f16x8 h;
  h[0] = a[0]; h[1] = a[1]; h[2] = a[2]; h[3] = a[3];
  h[4] = b[0]; h[5] = b[1]; h[6] = b[2]; h[7] = b[3];
  return h;
}

// DPP lane move (VALU pipe — replaces ds_bpermute-based __shfl_xor)
template <int CTRL>
static __device__ __forceinline__ float dppf(float v) {
  int x = __float_as_int(v);
  x = __builtin_amdgcn_update_dpp(x, x, CTRL, 0xf, 0xf, false);
  return __int_as_float(x);
}
// butterfly over 16-lane row: xor1,xor2 via quad_perm; cross-4 via half_mirror;
// cross-8 via row_mirror (bijective group swaps — valid for max/sum reduce)
static __device__ __forceinline__ float rmax16(float v) {
  v = fmaxf(v, dppf<0xB1>(v));    // quad_perm [1,0,3,2]
  v = fmaxf(v, dppf<0x4E>(v));    // quad_perm [2,3,0,1]
  v = fmaxf(v, dppf<0x141>(v));   // row_half_mirror
  v = fmaxf(v, dppf<0x140>(v));   // row_mirror
  return v;
}
static __device__ __forceinline__ float rsum16(float v) {
  v += dppf<0xB1>(v);
  v += dppf<0x4E>(v);
  v += dppf<0x141>(v);
  v += dppf<0x140>(v);
  return v;
}

__global__ __launch_bounds__(256, 2)
void attn_fwd(const float* __restrict__ Qp, const float* __restrict__ Kp,
              const float* __restrict__ Vp, const int* __restrict__ VLp,
              float* __restrict__ Op) {
  // double-buffered tiles: ONE barrier per K-tile (80 KB -> 2 blocks/CU)
  __shared__ f16 sK[2][BK][DKP];   // ROW-PERMUTED: pos p holds key (p&15)*4+(p>>4)
  __shared__ f16 sVT[2][D][BKP];   // V tile transposed [d][kk]
  __shared__ f16 sP[4][16][BKP];   // per-wave P tile [row][kk]

  const int tid  = threadIdx.x;
  const int wave = tid >> 6, lane = tid & 63;
  const int l16  = lane & 15, quad = lane >> 4;

  // Mapping: XCD affinity (b&7 == id&7 -> same-b q-tiles share an XCD L2)
  // AND decorrelated CU pairing: blocks id, id+256 get batches b, b+16
  // (independent vl) instead of the same batch (R4's straggler pathology).
  const int id = blockIdx.x;
  const int qt = id >> 5;                                   // 0..15
  const int b  = (id & 7) | (((((id >> 3) & 3) + (qt >> 2)) & 3) << 3);
  const int vl = VLp[b];

  const float* Kb = Kp + (size_t)b * KL * D;
  const float* Vb = Vp + (size_t)b * KL * D;
  const int ntiles = (vl + BK - 1) / BK;  // fully-masked tiles contribute exactly 0

  float4 kreg[8], vreg[8];

  // ---- prologue: load tile 0 into regs
  {
    const float4* Kt = (const float4*)Kb;
    #pragma unroll
    for (int i = 0; i < 4; ++i) {
      int c = tid + i * 256;            // chunk: row = c>>4, 8 floats at (c&15)*8
      int row = c >> 4, d04 = (c & 15) * 2;
      kreg[2 * i]     = Kt[row * 32 + d04];
      kreg[2 * i + 1] = Kt[row * 32 + d04 + 1];
    }
    #pragma unroll
    for (int i = 0; i < 2; ++i) {
      int f = tid + i * 256;
      const float* base = Vb + (size_t)((f & 15) * 4) * D + (f >> 4) * 4;
      vreg[i * 4 + 0] = *(const float4*)(base);
      vreg[i * 4 + 1] = *(const float4*)(base + D);
      vreg[i * 4 + 2] = *(const float4*)(base + 2 * D);
      vreg[i * 4 + 3] = *(const float4*)(base + 3 * D);
    }
  }

  // ---- Q fragments (A-operand layout), registers for all K tiles
  const float* Qb = Qp + ((size_t)(b * QL + qt * BQ + wave * 16 + l16)) * D;
  f16x8 qfrag[4];
  #pragma unroll
  for (int kc = 0; kc < 4; ++kc) {
    const float* p = Qb + kc * 32 + quad * 8;
    qfrag[kc] = pk8(*(const float4*)p, *(const float4*)(p + 4));
  }

  float m2[4]   = {-INFINITY, -INFINITY, -INFINITY, -INFINITY};
  float lsum[4] = {0.f, 0.f, 0.f, 0.f};
  f32x4 o[8];
  #pragma unroll
  for (int dt = 0; dt < 8; ++dt) o[dt] = (f32x4){0.f, 0.f, 0.f, 0.f};

  // ---- drain tile 0 into buffer 0 (K: 4x ds_write_b128)
  #pragma unroll
  for (int i = 0; i < 4; ++i) {
    int c = tid + i * 256;
    int row = c >> 4, d0 = (c & 15) * 8;
    int rp = (row & 3) * 16 + (row >> 2);
    *(f16x8*)&sK[0][rp][d0] = pk8(kreg[2 * i], kreg[2 * i + 1]);
  }
  #pragma unroll
  for (int i = 0; i < 2; ++i) {
    int f = tid + i * 256;
    int k0 = (f & 15) * 4, d0 = (f >> 4) * 4;
    float4 r0 = vreg[i*4+0], r1 = vreg[i*4+1], r2 = vreg[i*4+2], r3 = vreg[i*4+3];
    *(f16x4*)&sVT[0][d0 + 0][k0] = pk4(r0.x, r1.x, r2.x, r3.x);
    *(f16x4*)&sVT[0][d0 + 1][k0] = pk4(r0.y, r1.y, r2.y, r3.y);
    *(f16x4*)&sVT[0][d0 + 2][k0] = pk4(r0.z, r1.z, r2.z, r3.z);
    *(f16x4*)&sVT[0][d0 + 3][k0] = pk4(r0.w, r1.w, r2.w, r3.w);
  }
  __syncthreads();

  for (int t = 0; t < ntiles; ++t) {
    const int cur = t & 1, nxt = cur ^ 1;
    const bool more = (t + 1 < ntiles);

    // ---- issue global loads for tile t+1 (land during compute)
    if (more) {
      const float4* Kt = (const float4*)(Kb + (size_t)(t + 1) * BK * D);
      #pragma unroll
      for (int i = 0; i < 4; ++i) {
        int c = tid + i * 256;
        int row = c >> 4, d04 = (c & 15) * 2;
        kreg[2 * i]     = Kt[row * 32 + d04];
        kreg[2 * i + 1] = Kt[row * 32 + d04 + 1];
      }
      const float* Vt = Vb + (size_t)(t + 1) * BK * D;
      #pragma unroll
      for (int i = 0; i < 2; ++i) {
        int f = tid + i * 256;
        const float* base = Vt + (size_t)((f & 15) * 4) * D + (f >> 4) * 4;
        vreg[i * 4 + 0] = *(const float4*)(base);
        vreg[i * 4 + 1] = *(const float4*)(base + D);
        vreg[i * 4 + 2] = *(const float4*)(base + 2 * D);
        vreg[i * 4 + 3] = *(const float4*)(base + 3 * D);
      }
    }

    // ---- S = Q K^T : 4 ct x 4 kc MFMA
    // LDS row ct*16+l16 holds actual key kk = l16*4 + ct (permuted staging)
    f32x4 s[4];
    #pragma unroll
    for (int ct = 0; ct < 4; ++ct) {
      f32x4 c = (f32x4){0.f, 0.f, 0.f, 0.f};
      #pragma unroll
      for (int kc = 0; kc < 4; ++kc) {
        f16x8 kf = *(const f16x8*)&sK[cur][ct * 16 + l16][kc * 32 + quad * 8];
        c = __builtin_amdgcn_mfma_f32_16x16x32_f16(qfrag[kc], kf, c, 0, 0, 0);
      }
      s[ct] = c;
    }

    // ---- scale into log2 domain + key-padding mask (kk = t*64 + l16*4 + ct)
    #pragma unroll
    for (int ct = 0; ct < 4; ++ct) {
      bool ok = (t * BK + l16 * 4 + ct) < vl;
      #pragma unroll
      for (int r = 0; r < 4; ++r)
        s[ct][r] = ok ? s[ct][r] * CSC : -1.0e9f;
    }

    // ---- online softmax (DPP reductions — VALU pipe, no LDS)
    float mnew[4], alpha[4];
    #pragma unroll
    for (int r = 0; r < 4; ++r) {
      float v = fmaxf(fmaxf(s[0][r], s[1][r]), fmaxf(s[2][r], s[3][r]));
      v = rmax16(v);
      mnew[r]  = fmaxf(m2[r], v);
      alpha[r] = __builtin_amdgcn_exp2f(m2[r] - mnew[r]);
      m2[r]    = mnew[r];
    }
    #pragma unroll
    for (int r = 0; r < 4; ++r) {
      float ls = 0.f;
      #pragma unroll
      for (int ct = 0; ct < 4; ++ct) {
        float p = __builtin_amdgcn_exp2f(s[ct][r] - mnew[r]);
        s[ct][r] = p;
        ls += p;
      }
      lsum[r] = lsum[r] * alpha[r] + rsum16(ls);
      // P -> LDS: lane's 4 ct-values are kk-contiguous (l16*4+ct) -> b64
      *(f16x4*)&sP[wave][quad * 4 + r][l16 * 4] =
          pk4(s[0][r], s[1][r], s[2][r], s[3][r]);
      #pragma unroll
      for (int dt = 0; dt < 8; ++dt) o[dt][r] *= alpha[r];
    }

    // sP is wave-private: in-wave DS ordering + waitcnt suffices (no barrier)
    asm volatile("s_waitcnt lgkmcnt(0)" ::: "memory");

    // ---- O += P V
    #pragma unroll
    for (int ks = 0; ks < 2; ++ks) {
      f16x8 pf = *(const f16x8*)&sP[wave][l16][ks * 32 + quad * 8];
      #pragma unroll
      for (int dt = 0; dt < 8; ++dt) {
        f16x8 vf = *(const f16x8*)&sVT[cur][dt * 16 + l16][ks * 32 + quad * 8];
        o[dt] = __builtin_amdgcn_mfma_f32_16x16x32_f16(pf, vf, o[dt], 0, 0, 0);
      }
    }

    // ---- drain prefetch regs into the other buffer
    if (more) {
      #pragma unroll
      for (int i = 0; i < 4; ++i) {
        int c = tid + i * 256;
        int row = c >> 4, d0 = (c & 15) * 8;
        int rp = (row & 3) * 16 + (row >> 2);
        *(f16x8*)&sK[nxt][rp][d0] = pk8(kreg[2 * i], kreg[2 * i + 1]);
      }
      #pragma unroll
      for (int i = 0; i < 2; ++i) {
        int f = tid + i * 256;
        int k0 = (f & 15) * 4, d0 = (f >> 4) * 4;
        float4 r0 = vreg[i*4+0], r1 = vreg[i*4+1], r2 = vreg[i*4+2], r3 = vreg[i*4+3];
        *(f16x4*)&sVT[nxt][d0 + 0][k0] = pk4(r0.x, r1.x, r2.x, r3.x);
        *(f16x4*)&sVT[nxt][d0 + 1][k0] = pk4(r0.y, r1.y, r2.y, r3.y);
        *(f16x4*)&sVT[nxt][d0 + 2][k0] = pk4(r0.z, r1.z, r2.z, r3.z);
        *(f16x4*)&sVT[nxt][d0 + 3][k0] = pk4(r0.w, r1.w, r2.w, r3.w);
      }
    }
    __syncthreads();
  }

  // ---- epilogue: O /= l, C-layout store (64B segments per 16 lanes)
  float* Ob = Op + ((size_t)(b * QL + qt * BQ + wave * 16)) * D;
  #pragma unroll
  for (int r = 0; r < 4; ++r) {
    float inv = 1.0f / lsum[r];
    int row = quad * 4 + r;
    #pragma unroll
    for (int dt = 0; dt < 8; ++dt)
      Ob[(size_t)row * D + dt * 16 + l16] = o[dt][r] * inv;
  }
}

extern "C" void kernel_launch(void* const* d_in, const int* in_sizes, int n_in,
                              void* d_out, int out_size, void* d_ws, size_t ws_size,
                              hipStream_t stream) {
  const float* Qp = (const float*)d_in[0];
  const float* Kp = (const float*)d_in[1];
  const float* Vp = (const float*)d_in[2];
  const int*   VL = (const int*)d_in[3];
  float* Op = (float*)d_out;

  attn_fwd<<<dim3(QL / BQ * BATCH), dim3(256), 0, stream>>>(Qp, Kp, Vp, VL, Op);
}

// Round 9
// 118.348 us; speedup vs baseline: 3.0260x; 1.0211x over previous
//
#include <hip/hip_runtime.h>
#include <math.h>

typedef _Float16 f16;
typedef __attribute__((ext_vector_type(8))) _Float16 f16x8;
typedef __attribute__((ext_vector_type(4))) _Float16 f16x4;
typedef __attribute__((ext_vector_type(4))) float f32x4;

constexpr int BATCH = 32;
constexpr int QL = 1024;
constexpr int KL = 1024;
constexpr int D = 128;
constexpr int BQ = 64;    // query rows per block (16 per wave)
constexpr int BK = 64;    // key rows per tile
constexpr int DKP = 136;  // sK row pitch in halves (272 B, 16B-aligned rows)
constexpr int BKP = 72;   // sVT/sP row pitch in halves (144 B)

// scale * log2(e): softmax computed in exp2 domain
#define CSC 0.12752863187087177f

static __device__ __forceinline__ f16x4 pk4(float x, float y, float z, float w) {
  auto a = __builtin_amdgcn_cvt_pkrtz(x, y);
  auto b = __builtin_amdgcn_cvt_pkrtz(z, w);
  f16x4 h;
  h[0] = (f16)a[0]; h[1] = (f16)a[1]; h[2] = (f16)b[0]; h[3] = (f16)b[1];
  return h;
}
static __device__ __forceinline__ f16x8 pk8(float4 u, float4 v) {
  f16x4 a = pk4(u.x, u.y, u.z, u.w);
  f16x4 b = pk4(v.x, v.y, v.z, v.w);
  f16x8 h;
  h[0] = a[0]; h[1] = a[1]; h[2] = a[2]; h[3] = a[3];
  h[4] = b[0]; h[5] = b[1]; h[6] = b[2]; h[7] = b[3];
  return h;
}

// DPP lane move (VALU pipe — replaces ds_bpermute-based __shfl_xor)
template <int CTRL>
static __device__ __forceinline__ float dppf(float v) {
  int x = __float_as_int(v);
  x = __builtin_amdgcn_update_dpp(x, x, CTRL, 0xf, 0xf, false);
  return __int_as_float(x);
}
static __device__ __forceinline__ float rmax16(float v) {
  v = fmaxf(v, dppf<0xB1>(v));    // quad_perm [1,0,3,2]
  v = fmaxf(v, dppf<0x4E>(v));    // quad_perm [2,3,0,1]
  v = fmaxf(v, dppf<0x141>(v));   // row_half_mirror
  v = fmaxf(v, dppf<0x140>(v));   // row_mirror
  return v;
}
static __device__ __forceinline__ float rsum16(float v) {
  v += dppf<0xB1>(v);
  v += dppf<0x4E>(v);
  v += dppf<0x141>(v);
  v += dppf<0x140>(v);
  return v;
}

__global__ __launch_bounds__(256, 2)
void attn_fwd(const float* __restrict__ Qp, const float* __restrict__ Kp,
              const float* __restrict__ Vp, const int* __restrict__ VLp,
              float* __restrict__ Op) {
  // double-buffered tiles: ONE barrier per K-tile (80 KB -> 2 blocks/CU)
  __shared__ f16 sK[2][BK][DKP];   // ROW-PERMUTED: pos p holds key (p&15)*4+(p>>4)
  __shared__ f16 sVT[2][D][BKP];   // V tile transposed [d][kk]
  __shared__ f16 sP[4][16][BKP];   // per-wave P tile [row][kk]
  __shared__ int sN[32];
  __shared__ int sB;

  const int tid  = threadIdx.x;
  const int wave = tid >> 6, lane = tid & 63;
  const int l16  = lane & 15, quad = lane >> 4;

  // ---- LPT-balanced static schedule, computed from valid_lens.
  // Items: 512 (b,qt), cost = ntiles(b). Sorted desc by cost (ties by b).
  // Block id -> item s: c = id&255; s = (id<256) ? c : 511-c.
  // Round-robin dispatch puts blocks c and c+256 on one CU -> that CU gets
  // items c (expensive end) and 511-c (cheap end): pair sums ~uniform (~18
  // tile-units vs 31 for random pairing). If dispatch differs, this
  // degrades to random pairing = R8 behavior, no worse.
  if (tid < 32) sN[tid] = (VLp[tid] + BK - 1) / BK;
  __syncthreads();
  if (tid < 32) {
    int nb = sN[tid], r = 0;
    #pragma unroll
    for (int k = 0; k < 32; ++k) {
      int nk = sN[k];
      r += (nk > nb) || (nk == nb && k < tid);
    }
    // batch tid owns sorted items [16r, 16r+16)
    sN[tid] = r;
  }
  __syncthreads();
  const int c = blockIdx.x & 255;
  const int s = (blockIdx.x < 256) ? c : (511 - c);
  if (tid < 32 && sN[tid] == (s >> 4)) sB = tid;
  __syncthreads();
  const int b  = sB;
  const int qt = s & 15;
  const int vl = VLp[b];

  const float* Kb = Kp + (size_t)b * KL * D;
  const float* Vb = Vp + (size_t)b * KL * D;
  const int ntiles = (vl + BK - 1) / BK;  // fully-masked tiles contribute exactly 0

  float4 kreg[8], vreg[8];

  // ---- prologue: load tile 0 into regs
  {
    const float4* Kt = (const float4*)Kb;
    #pragma unroll
    for (int i = 0; i < 4; ++i) {
      int cc = tid + i * 256;           // chunk: row = cc>>4, 8 floats at (cc&15)*8
      int row = cc >> 4, d04 = (cc & 15) * 2;
      kreg[2 * i]     = Kt[row * 32 + d04];
      kreg[2 * i + 1] = Kt[row * 32 + d04 + 1];
    }
    #pragma unroll
    for (int i = 0; i < 2; ++i) {
      int f = tid + i * 256;
      const float* base = Vb + (size_t)((f & 15) * 4) * D + (f >> 4) * 4;
      vreg[i * 4 + 0] = *(const float4*)(base);
      vreg[i * 4 + 1] = *(const float4*)(base + D);
      vreg[i * 4 + 2] = *(const float4*)(base + 2 * D);
      vreg[i * 4 + 3] = *(const float4*)(base + 3 * D);
    }
  }

  // ---- Q fragments (A-operand layout), registers for all K tiles
  const float* Qb = Qp + ((size_t)(b * QL + qt * BQ + wave * 16 + l16)) * D;
  f16x8 qfrag[4];
  #pragma unroll
  for (int kc = 0; kc < 4; ++kc) {
    const float* p = Qb + kc * 32 + quad * 8;
    qfrag[kc] = pk8(*(const float4*)p, *(const float4*)(p + 4));
  }

  float m2[4]   = {-INFINITY, -INFINITY, -INFINITY, -INFINITY};
  float lsum[4] = {0.f, 0.f, 0.f, 0.f};
  f32x4 o[8];
  #pragma unroll
  for (int dt = 0; dt < 8; ++dt) o[dt] = (f32x4){0.f, 0.f, 0.f, 0.f};

  // ---- drain tile 0 into buffer 0 (K: 4x ds_write_b128)
  #pragma unroll
  for (int i = 0; i < 4; ++i) {
    int cc = tid + i * 256;
    int row = cc >> 4, d0 = (cc & 15) * 8;
    int rp = (row & 3) * 16 + (row >> 2);
    *(f16x8*)&sK[0][rp][d0] = pk8(kreg[2 * i], kreg[2 * i + 1]);
  }
  #pragma unroll
  for (int i = 0; i < 2; ++i) {
    int f = tid + i * 256;
    int k0 = (f & 15) * 4, d0 = (f >> 4) * 4;
    float4 r0 = vreg[i*4+0], r1 = vreg[i*4+1], r2 = vreg[i*4+2], r3 = vreg[i*4+3];
    *(f16x4*)&sVT[0][d0 + 0][k0] = pk4(r0.x, r1.x, r2.x, r3.x);
    *(f16x4*)&sVT[0][d0 + 1][k0] = pk4(r0.y, r1.y, r2.y, r3.y);
    *(f16x4*)&sVT[0][d0 + 2][k0] = pk4(r0.z, r1.z, r2.z, r3.z);
    *(f16x4*)&sVT[0][d0 + 3][k0] = pk4(r0.w, r1.w, r2.w, r3.w);
  }
  __syncthreads();

  for (int t = 0; t < ntiles; ++t) {
    const int cur = t & 1, nxt = cur ^ 1;
    const bool more = (t + 1 < ntiles);

    // ---- issue global loads for tile t+1 (land during compute)
    if (more) {
      const float4* Kt = (const float4*)(Kb + (size_t)(t + 1) * BK * D);
      #pragma unroll
      for (int i = 0; i < 4; ++i) {
        int cc = tid + i * 256;
        int row = cc >> 4, d04 = (cc & 15) * 2;
        kreg[2 * i]     = Kt[row * 32 + d04];
        kreg[2 * i + 1] = Kt[row * 32 + d04 + 1];
      }
      const float* Vt = Vb + (size_t)(t + 1) * BK * D;
      #pragma unroll
      for (int i = 0; i < 2; ++i) {
        int f = tid + i * 256;
        const float* base = Vt + (size_t)((f & 15) * 4) * D + (f >> 4) * 4;
        vreg[i * 4 + 0] = *(const float4*)(base);
        vreg[i * 4 + 1] = *(const float4*)(base + D);
        vreg[i * 4 + 2] = *(const float4*)(base + 2 * D);
        vreg[i * 4 + 3] = *(const float4*)(base + 3 * D);
      }
    }

    // ---- S = Q K^T : 4 ct x 4 kc MFMA
    // LDS row ct*16+l16 holds actual key kk = l16*4 + ct (permuted staging)
    f32x4 sv[4];
    #pragma unroll
    for (int ct = 0; ct < 4; ++ct) {
      f32x4 cacc = (f32x4){0.f, 0.f, 0.f, 0.f};
      #pragma unroll
      for (int kc = 0; kc < 4; ++kc) {
        f16x8 kf = *(const f16x8*)&sK[cur][ct * 16 + l16][kc * 32 + quad * 8];
        cacc = __builtin_amdgcn_mfma_f32_16x16x32_f16(qfrag[kc], kf, cacc, 0, 0, 0);
      }
      sv[ct] = cacc;
    }

    // ---- scale into log2 domain + key-padding mask (kk = t*64 + l16*4 + ct)
    #pragma unroll
    for (int ct = 0; ct < 4; ++ct) {
      bool ok = (t * BK + l16 * 4 + ct) < vl;
      #pragma unroll
      for (int r = 0; r < 4; ++r)
        sv[ct][r] = ok ? sv[ct][r] * CSC : -1.0e9f;
    }

    // ---- online softmax (DPP reductions — VALU pipe, no LDS)
    float mnew[4], alpha[4];
    #pragma unroll
    for (int r = 0; r < 4; ++r) {
      float v = fmaxf(fmaxf(sv[0][r], sv[1][r]), fmaxf(sv[2][r], sv[3][r]));
      v = rmax16(v);
      mnew[r]  = fmaxf(m2[r], v);
      alpha[r] = __builtin_amdgcn_exp2f(m2[r] - mnew[r]);
      m2[r]    = mnew[r];
    }
    #pragma unroll
    for (int r = 0; r < 4; ++r) {
      float ls = 0.f;
      #pragma unroll
      for (int ct = 0; ct < 4; ++ct) {
        float p = __builtin_amdgcn_exp2f(sv[ct][r] - mnew[r]);
        sv[ct][r] = p;
        ls += p;
      }
      lsum[r] = lsum[r] * alpha[r] + rsum16(ls);
      // P -> LDS: lane's 4 ct-values are kk-contiguous (l16*4+ct) -> b64
      *(f16x4*)&sP[wave][quad * 4 + r][l16 * 4] =
          pk4(sv[0][r], sv[1][r], sv[2][r], sv[3][r]);
      #pragma unroll
      for (int dt = 0; dt < 8; ++dt) o[dt][r] *= alpha[r];
    }

    // sP is wave-private: in-wave DS ordering + waitcnt suffices (no barrier)
    asm volatile("s_waitcnt lgkmcnt(0)" ::: "memory");

    // ---- O += P V
    #pragma unroll
    for (int ks = 0; ks < 2; ++ks) {
      f16x8 pf = *(const f16x8*)&sP[wave][l16][ks * 32 + quad * 8];
      #pragma unroll
      for (int dt = 0; dt < 8; ++dt) {
        f16x8 vf = *(const f16x8*)&sVT[cur][dt * 16 + l16][ks * 32 + quad * 8];
        o[dt] = __builtin_amdgcn_mfma_f32_16x16x32_f16(pf, vf, o[dt], 0, 0, 0);
      }
    }

    // ---- drain prefetch regs into the other buffer
    if (more) {
      #pragma unroll
      for (int i = 0; i < 4; ++i) {
        int cc = tid + i * 256;
        int row = cc >> 4, d0 = (cc & 15) * 8;
        int rp = (row & 3) * 16 + (row >> 2);
        *(f16x8*)&sK[nxt][rp][d0] = pk8(kreg[2 * i], kreg[2 * i + 1]);
      }
      #pragma unroll
      for (int i = 0; i < 2; ++i) {
        int f = tid + i * 256;
        int k0 = (f & 15) * 4, d0 = (f >> 4) * 4;
        float4 r0 = vreg[i*4+0], r1 = vreg[i*4+1], r2 = vreg[i*4+2], r3 = vreg[i*4+3];
        *(f16x4*)&sVT[nxt][d0 + 0][k0] = pk4(r0.x, r1.x, r2.x, r3.x);
        *(f16x4*)&sVT[nxt][d0 + 1][k0] = pk4(r0.y, r1.y, r2.y, r3.y);
        *(f16x4*)&sVT[nxt][d0 + 2][k0] = pk4(r0.z, r1.z, r2.z, r3.z);
        *(f16x4*)&sVT[nxt][d0 + 3][k0] = pk4(r0.w, r1.w, r2.w, r3.w);
      }
    }
    __syncthreads();
  }

  // ---- epilogue: O /= l, C-layout store (64B segments per 16 lanes)
  float* Ob = Op + ((size_t)(b * QL + qt * BQ + wave * 16)) * D;
  #pragma unroll
  for (int r = 0; r < 4; ++r) {
    float inv = 1.0f / lsum[r];
    int row = quad * 4 + r;
    #pragma unroll
    for (int dt = 0; dt < 8; ++dt)
      Ob[(size_t)row * D + dt * 16 + l16] = o[dt][r] * inv;
  }
}

extern "C" void kernel_launch(void* const* d_in, const int* in_sizes, int n_in,
                              void* d_out, int out_size, void* d_ws, size_t ws_size,
                              hipStream_t stream) {
  const float* Qp = (const float*)d_in[0];
  const float* Kp = (const float*)d_in[1];
  const float* Vp = (const float*)d_in[2];
  const int*   VL = (const int*)d_in[3];
  float* Op = (float*)d_out;

  attn_fwd<<<dim3(QL / BQ * BATCH), dim3(256), 0, stream>>>(Qp, Kp, Vp, VL, Op);
}